// Round 8
// baseline (301.506 us; speedup 1.0000x reference)
//
#include <hip/hip_runtime.h>

// ---------------------------------------------------------------------------
// LocalitySelfAttention: y = proj( attn(x@Wqkv^T) ) for B=8,N=2048,C=384,H=6
// All internal compute bf16 MFMA + fp32 accum. Output fp32.
// R8: attn pipelined one tile ahead (pack(t) || QK^T(t+1)), V read direct
// from L2 (no LDS staging), K staged via global_load_lds with pre-swizzled
// source, row-sum on VALU in pack phase (ones-MFMA dropped).
// ---------------------------------------------------------------------------

using f32x4 = __attribute__((ext_vector_type(4))) float;
using s16x8 = __attribute__((ext_vector_type(8))) short;
using u16x4 = __attribute__((ext_vector_type(4))) unsigned short;
using u32x2 = __attribute__((ext_vector_type(2))) unsigned int;
using u32x4 = __attribute__((ext_vector_type(4))) unsigned int;
typedef unsigned short u16;
typedef unsigned int u32;

#define MFMA16(a, b, c) __builtin_amdgcn_mfma_f32_16x16x32_bf16(a, b, c, 0, 0, 0)
#define LOG2E 1.4426950408889634f
#define SQRTC 19.595917942265423f

__device__ __forceinline__ u16 f2bf(float f) {
  u32 u = __float_as_uint(f);
  u += 0x7fffu + ((u >> 16) & 1u);   // RNE
  return (u16)(u >> 16);
}

__device__ __forceinline__ u32 cvtpk(float lo, float hi) {
  u32 r;
  asm("v_cvt_pk_bf16_f32 %0, %1, %2" : "=v"(r) : "v"(lo), "v"(hi));
  return r;
}

__device__ __forceinline__ float fexp2(float x) {  // 2^x, single v_exp_f32
  float r;
  asm("v_exp_f32 %0, %1" : "=v"(r) : "v"(x));
  return r;
}

__device__ __forceinline__ void gld16(const void* g, void* l) {
  __builtin_amdgcn_global_load_lds((const __attribute__((address_space(1))) void*)g,
                                   (__attribute__((address_space(3))) void*)l, 16, 0, 0);
}

// --------------------------- fp32 -> bf16 convert (both weights) ------------
__global__ __launch_bounds__(256) void k_cvt2(const float* __restrict__ A,
                                              u16* __restrict__ Oa,
                                              const float* __restrict__ B,
                                              u16* __restrict__ Ob) {
  const int bid = blockIdx.x;
  const float* in;
  u16* out;
  size_t i;
  if (bid < 432) { in = A; out = Oa; i = (size_t)bid * 256 + threadIdx.x; }
  else           { in = B; out = Ob; i = (size_t)(bid - 432) * 256 + threadIdx.x; }
  f32x4 v = *(const f32x4*)(in + i * 4);
  u16x4 o;
  o[0] = f2bf(v[0]); o[1] = f2bf(v[1]); o[2] = f2bf(v[2]); o[3] = f2bf(v[3]);
  *(u16x4*)(out + i * 4) = o;
}

// --------------------------- QKV GEMM (M=16384,N=1152,K=384) ----------------
__global__ __launch_bounds__(256) void k_qkv(const float* __restrict__ X,
                                             const u16* __restrict__ W,
                                             const float* __restrict__ temp,
                                             u16* __restrict__ Qt,
                                             u16* __restrict__ Kb,
                                             u16* __restrict__ Vt) {
  __shared__ u16 As[2][128 * 32];
  __shared__ u16 Bs[2][128 * 32];
  const int tid = threadIdx.x, w = tid >> 6, l = tid & 63, lr = l & 15, lg = l >> 4;
  const int id = blockIdx.y * 9 + blockIdx.x;
  const int swz = (id & 7) * 144 + (id >> 3);
  const int tn = (swz % 9) * 128, tm = (swz / 9) * 128;
  const int wr = w >> 1, wc = w & 1;
  const int r0 = tid >> 2, c8 = (tid & 3) * 8;
  const int ar = tid >> 1, ac = (tid & 1) * 16;

  f32x4 acc[4][4] = {};
  f32x4 a4[4];

  auto issueA = [&](int kt) {
    const float* xp = X + (size_t)(tm + ar) * 384 + kt * 32 + ac;
    a4[0] = *(const f32x4*)(xp);
    a4[1] = *(const f32x4*)(xp + 4);
    a4[2] = *(const f32x4*)(xp + 8);
    a4[3] = *(const f32x4*)(xp + 12);
  };
  auto commitA = [&](int buf) {
    u32x4 h0, h1;
    h0[0] = cvtpk(a4[0][0], a4[0][1]); h0[1] = cvtpk(a4[0][2], a4[0][3]);
    h0[2] = cvtpk(a4[1][0], a4[1][1]); h0[3] = cvtpk(a4[1][2], a4[1][3]);
    h1[0] = cvtpk(a4[2][0], a4[2][1]); h1[1] = cvtpk(a4[2][2], a4[2][3]);
    h1[2] = cvtpk(a4[3][0], a4[3][1]); h1[3] = cvtpk(a4[3][2], a4[3][3]);
    *(u32x4*)&As[buf][ar * 32 + ac] = h0;
    *(u32x4*)&As[buf][ar * 32 + ac + 8] = h1;
  };
  auto stageB = [&](int buf, int kt) {
    const int k0 = kt * 32;
    char* db = (char*)(&Bs[buf][0]) + (w << 10);
    gld16(W + (size_t)(tn + r0) * 384 + k0 + c8, db);
    gld16(W + (size_t)(tn + 64 + r0) * 384 + k0 + c8, db + 4096);
  };

  issueA(0); stageB(0, 0); commitA(0);
  for (int kt = 0; kt < 12; ++kt) {
    __syncthreads();
    if (kt < 11) { issueA(kt + 1); stageB((kt + 1) & 1, kt + 1); }
    const int buf = kt & 1;
    s16x8 af[4], bfr[4];
    for (int mi = 0; mi < 4; mi++)
      af[mi] = *(const s16x8*)&As[buf][(wr * 64 + mi * 16 + lr) * 32 + lg * 8];
    for (int ni = 0; ni < 4; ni++)
      bfr[ni] = *(const s16x8*)&Bs[buf][(wc * 64 + ni * 16 + lr) * 32 + lg * 8];
    for (int mi = 0; mi < 4; mi++)
      for (int ni = 0; ni < 4; ni++)
        acc[mi][ni] = MFMA16(af[mi], bfr[ni], acc[mi][ni]);
    if (kt < 11) commitA((kt + 1) & 1);
  }

  const int which = (tn + wc * 64) / 384;
  const int bidx = (tm >> 11);
  for (int mi = 0; mi < 4; mi++)
    for (int ni = 0; ni < 4; ni++) {
      const int n = tn + wc * 64 + ni * 16 + lr;
      const int c = n - which * 384;
      const int h = c >> 6, d = c & 63;
      const size_t bh = (size_t)(bidx * 6 + h);
      if (which == 1) {
        for (int j = 0; j < 4; j++) {
          const int pos = (tm + wr * 64 + mi * 16 + lg * 4 + j) & 2047;
          Kb[(bh * 2048 + pos) * 64 + d] = f2bf(acc[mi][ni][j]);
        }
      } else {
        const float mult = (which == 0) ? (LOG2E / (SQRTC * temp[h])) : 1.0f;
        const int pos0 = (tm + wr * 64 + mi * 16 + lg * 4) & 2047;
        u16x4 vv;
        vv[0] = f2bf(acc[mi][ni][0] * mult); vv[1] = f2bf(acc[mi][ni][1] * mult);
        vv[2] = f2bf(acc[mi][ni][2] * mult); vv[3] = f2bf(acc[mi][ni][3] * mult);
        u16* dst = (which == 0) ? Qt : Vt;
        *(u16x4*)&dst[(bh * 64 + d) * 2048 + pos0] = vv;
      }
    }
}

// --------------------------- Flash attention (pipelined) --------------------
// grid = 48 bh * 16 q-tiles (XCD-swizzled). Block: 4 waves x 32 q-rows.
// K: dbuf XOR-swizzled LDS via global_load_lds w/ pre-swizzled source.
// V: direct from global (L2-resident per XCD). pack(t) || QK^T(t+1).
__global__ __launch_bounds__(256, 3) void k_attn(const u16* __restrict__ Qt,
                                                 const u16* __restrict__ Kb,
                                                 const u16* __restrict__ Vt,
                                                 u16* __restrict__ AO) {
  __shared__ u16 Ks[2][64 * 64];
  __shared__ u16 Ps[4][32 * 72];
  const int tid = threadIdx.x, w = tid >> 6, l = tid & 63, lr = l & 15, lg = l >> 4;
  const int orig = blockIdx.x;
  const int rm = (orig & 7) * 96 + (orig >> 3);
  const int qt = rm & 15, bh = rm >> 4;
  const int h = bh % 6, b = bh / 6;
  const size_t base = (size_t)bh << 17;
  const int q0 = qt * 128 + w * 32;
  const int maskKt = q0 >> 6;
  const int qo = q0 & 63;

  // Q fragments gathered from Qt[bh][d][pos] (once per block)
  s16x8 qf[2][2];
  for (int mi = 0; mi < 2; mi++)
    for (int ks = 0; ks < 2; ks++) {
      const u16* qp = Qt + base + (size_t)(ks * 32 + lg * 8) * 2048 + q0 + mi * 16 + lr;
      s16x8 q;
      for (int e = 0; e < 8; ++e) q[e] = (short)qp[(size_t)e * 2048];
      qf[mi][ks] = q;
    }

  f32x4 o0[4] = {}, o1[4] = {};
  float sum0 = 0.f, sum1 = 0.f;

  // K staging: global_load_lds with pre-swizzled source.
  // Wave w writes LDS bytes [w*1024, w*1024+1024): linear (r = w*8 + (l>>3),
  // c = l&7); fetch global chunk (r, c^(r&7)) so swizzled content lands linear.
  const int kr = w * 8 + (l >> 3);
  const int kc = (l & 7) ^ (kr & 7);
  auto gldK = [&](int kt) {
    const int buf = kt & 1;
    u16* kd0 = &Ks[buf][0] + w * 512;
    u16* kd1 = &Ks[buf][2048] + w * 512;
    gld16(Kb + base + (size_t)(kt * 64 + kr) * 64 + kc * 8, kd0);
    gld16(Kb + base + (size_t)(kt * 64 + 32 + kr) * 64 + kc * 8, kd1);
  };

  // V fragments direct from global Vt[bh][d][pos]
  s16x8 vfr[2][4];
  auto issueV = [&](int kt) {
    for (int ks = 0; ks < 2; ++ks)
      for (int dj = 0; dj < 4; ++dj)
        vfr[ks][dj] = *(const s16x8*)(Vt + base + (size_t)(dj * 16 + lr) * 2048 +
                                      kt * 64 + ks * 32 + lg * 8);
  };

  const int lrs = (lr & 7) << 4;
  const int x0 = (lg * 16) ^ lrs;
  const int x1 = (64 + lg * 16) ^ lrs;

  auto qk = [&](int kt, f32x4 (&sn0)[4], f32x4 (&sn1)[4]) {
    const char* kbp = (const char*)&Ks[kt & 1][0];
    __builtin_amdgcn_s_setprio(1);
    for (int ni = 0; ni < 4; ++ni) {
      const int rb = (ni * 16 + lr) * 128;
      const s16x8 kf0 = *(const s16x8*)(kbp + (rb + x0));
      const s16x8 kf1 = *(const s16x8*)(kbp + (rb + x1));
      f32x4 z = {};
      sn0[ni] = MFMA16(kf0, qf[0][0], z);
      sn0[ni] = MFMA16(kf1, qf[0][1], sn0[ni]);
      sn1[ni] = MFMA16(kf0, qf[1][0], z);
      sn1[ni] = MFMA16(kf1, qf[1][1], sn1[ni]);
    }
    __builtin_amdgcn_s_setprio(0);
  };

  u16* const psw = &Ps[w][0];
  auto packHalf = [&](f32x4 (&st)[4], int rowoff, float& sum) {
    u16* pr = psw + (rowoff + lr) * 72 + lg * 4;
    float ls = 0.f;
    for (int ni = 0; ni < 4; ++ni) {
      float p0 = fexp2(st[ni][0]), p1 = fexp2(st[ni][1]);
      float p2 = fexp2(st[ni][2]), p3 = fexp2(st[ni][3]);
      ls += (p0 + p1) + (p2 + p3);
      u32x2 d2;
      d2[0] = cvtpk(p0, p1);
      d2[1] = cvtpk(p2, p3);
      *(u32x2*)(pr + ni * 16) = d2;
    }
    ls += __shfl_xor(ls, 16);
    ls += __shfl_xor(ls, 32);
    sum += ls;
  };
  auto maskDiag = [&](f32x4 (&s0)[4], f32x4 (&s1)[4]) {
    for (int ni = 0; ni < 4; ++ni)
      for (int j = 0; j < 4; ++j) {
        const int kvl = ni * 16 + lg * 4 + j;
        if (kvl == qo + lr)      s0[ni][j] = -1e30f;
        if (kvl == qo + 16 + lr) s1[ni][j] = -1e30f;
      }
  };
  auto pv = [&]() {
    const s16x8 pa0k0 = *(const s16x8*)((const char*)(psw + lr * 72) + 0 * 64 + lg * 16);
    const s16x8 pa0k1 = *(const s16x8*)((const char*)(psw + lr * 72) + 1 * 64 + lg * 16);
    const s16x8 pa1k0 = *(const s16x8*)((const char*)(psw + (16 + lr) * 72) + 0 * 64 + lg * 16);
    const s16x8 pa1k1 = *(const s16x8*)((const char*)(psw + (16 + lr) * 72) + 1 * 64 + lg * 16);
    __builtin_amdgcn_s_setprio(1);
    for (int dj = 0; dj < 4; ++dj) o0[dj] = MFMA16(pa0k0, vfr[0][dj], o0[dj]);
    for (int dj = 0; dj < 4; ++dj) o0[dj] = MFMA16(pa0k1, vfr[1][dj], o0[dj]);
    for (int dj = 0; dj < 4; ++dj) o1[dj] = MFMA16(pa1k0, vfr[0][dj], o1[dj]);
    for (int dj = 0; dj < 4; ++dj) o1[dj] = MFMA16(pa1k1, vfr[1][dj], o1[dj]);
    __builtin_amdgcn_s_setprio(0);
  };

  f32x4 stA0[4], stA1[4], stB0[4], stB1[4];

  // ---- prologue ----
  gldK(0);
  __syncthreads();                 // Ks[0] ready
  issueV(0);
  gldK(1);
  qk(0, stA0, stA1);               // S(0) from Ks[0]
  __syncthreads();                 // Ks[1] ready

  // ---- pipelined loop: tiles 0..30 in body (computes QK^T one ahead) ----
  auto body = [&](f32x4 (&sc0)[4], f32x4 (&sc1)[4],
                  f32x4 (&sn0)[4], f32x4 (&sn1)[4], int t) {
    if (t < 30) gldK(t + 2);
    if (t == maskKt) maskDiag(sc0, sc1);
    packHalf(sc0, 0, sum0);        // exp2/pack overlaps qk(t+1) MFMAs
    qk(t + 1, sn0, sn1);
    packHalf(sc1, 16, sum1);
    pv();                          // V(t) frags, Ps of this tile
    issueV(t + 1);                 // V(t+1) -> vfr (WAR after pv issue)
    __syncthreads();               // drains gldK(t+2); Ks[(t+2)&1] ready
  };

  for (int tb = 0; tb < 15; ++tb) {
    body(stA0, stA1, stB0, stB1, 2 * tb);
    body(stB0, stB1, stA0, stA1, 2 * tb + 1);
  }
  body(stA0, stA1, stB0, stB1, 30);
  // ---- tail: tile 31 ----
  if (31 == maskKt) maskDiag(stB0, stB1);
  packHalf(stB0, 0, sum0);
  packHalf(stB1, 16, sum1);
  pv();

  // ---- normalize + merge heads: AO[b][pos][h*64+d], bf16 ----
  // sum0/sum1 at lane (lr,lg) hold rowsum(q = lr / 16+lr); redistribute.
  f32x4 rv0, rv1;
  for (int j = 0; j < 4; ++j) {
    rv0[j] = 1.0f / __shfl(sum0, lg * 4 + j);
    rv1[j] = 1.0f / __shfl(sum1, lg * 4 + j);
  }
  const size_t aobase = (size_t)b * 2048 * 384 + (size_t)h * 64;
  for (int j = 0; j < 4; ++j) {
    const int pos0 = q0 + lg * 4 + j;
    const int pos1 = pos0 + 16;
    for (int dj = 0; dj < 4; ++dj) {
      AO[aobase + (size_t)pos0 * 384 + dj * 16 + lr] = f2bf(o0[dj][j] * rv0[j]);
      AO[aobase + (size_t)pos1 * 384 + dj * 16 + lr] = f2bf(o1[dj][j] * rv1[j]);
    }
  }
}

// --------------------------- Proj GEMM (M=16384,N=384,K=384) ----------------
__global__ __launch_bounds__(256) void k_proj(const u16* __restrict__ A,
                                              const u16* __restrict__ W,
                                              const float* __restrict__ bias,
                                              float* __restrict__ out) {
  __shared__ u16 As[2][128 * 32];
  __shared__ u16 Bs[2][64 * 32];
  const int tid = threadIdx.x, w = tid >> 6, l = tid & 63, lr = l & 15, lg = l >> 4;
  const int id = blockIdx.y * 6 + blockIdx.x;
  const int swz = (id & 7) * 96 + (id >> 3);
  const int tn = (swz % 6) * 64, tm = (swz / 6) * 128;
  const int r0 = tid >> 2, c8 = (tid & 3) * 8;

  f32x4 acc[2][4] = {};

  auto stage = [&](int buf, int kt) {
    const int k0 = kt * 32;
    char* da = (char*)(&As[buf][0]) + (w << 10);
    char* db = (char*)(&Bs[buf][0]) + (w << 10);
    gld16(A + (size_t)(tm + r0) * 384 + k0 + c8, da);
    gld16(A + (size_t)(tm + 64 + r0) * 384 + k0 + c8, da + 4096);
    gld16(W + (size_t)(tn + r0) * 384 + k0 + c8, db);
  };

  stage(0, 0);
  for (int kt = 0; kt < 12; ++kt) {
    __syncthreads();
    if (kt < 11) stage((kt + 1) & 1, kt + 1);
    const int buf = kt & 1;
    s16x8 af[2], bfr[4];
    for (int mi = 0; mi < 2; mi++)
      af[mi] = *(const s16x8*)&As[buf][(w * 32 + mi * 16 + lr) * 32 + lg * 8];
    for (int ni = 0; ni < 4; ni++)
      bfr[ni] = *(const s16x8*)&Bs[buf][(ni * 16 + lr) * 32 + lg * 8];
    for (int mi = 0; mi < 2; mi++)
      for (int ni = 0; ni < 4; ni++)
        acc[mi][ni] = MFMA16(af[mi], bfr[ni], acc[mi][ni]);
  }

  for (int mi = 0; mi < 2; mi++)
    for (int ni = 0; ni < 4; ni++) {
      const int n = tn + ni * 16 + lr;
      const float bn = bias[n];
      for (int j = 0; j < 4; j++) {
        const int m = tm + w * 32 + mi * 16 + lg * 4 + j;
        out[(size_t)m * 384 + n] = acc[mi][ni][j] + bn;
      }
    }
}

// --------------------------- launch -----------------------------------------
extern "C" void kernel_launch(void* const* d_in, const int* in_sizes, int n_in,
                              void* d_out, int out_size, void* d_ws, size_t ws_size,
                              hipStream_t stream) {
  const float* x      = (const float*)d_in[0];  // [8,2048,384]
  const float* qkv_w  = (const float*)d_in[1];  // [1152,384]
  const float* proj_w = (const float*)d_in[2];  // [384,384]
  const float* proj_b = (const float*)d_in[3];  // [384]
  const float* temp   = (const float*)d_in[4];  // [6]
  float* out = (float*)d_out;

  u16* wqkvb  = (u16*)d_ws;            // 442368
  u16* wprojb = wqkvb + 442368;        // 147456
  u16* Qt     = wprojb + 147456;       // 6291456
  u16* Kb     = Qt + 6291456;          // 6291456
  u16* Vtb    = Kb + 6291456;          // 6291456
  u16* AOb    = Vtb + 6291456;         // 6291456

  k_cvt2<<<576, 256, 0, stream>>>(qkv_w, wqkvb, proj_w, wprojb);
  k_qkv<<<dim3(9, 128), 256, 0, stream>>>(x, wqkvb, temp, Qt, Kb, Vtb);
  k_attn<<<768, 256, 0, stream>>>(Qt, Kb, Vtb, AOb);
  k_proj<<<dim3(6, 128), 256, 0, stream>>>(AOb, wprojb, proj_b, out);
}

// Round 9
// 130.551 us; speedup vs baseline: 2.3095x; 2.3095x over previous
//
#include <hip/hip_runtime.h>

// ---------------------------------------------------------------------------
// LocalitySelfAttention: y = proj( attn(x@Wqkv^T) ) for B=8,N=2048,C=384,H=6
// All internal compute bf16 MFMA + fp32 accum. Output fp32.
// R9: revert R8's V-direct (7x HBM overfetch); K AND V staged via
// global_load_lds w/ pre-swizzled source (no reg-staging), keep the
// pack(t) || QK^T(t+1) pipeline. K prefetch distance 2, V distance 1.
// ---------------------------------------------------------------------------

using f32x4 = __attribute__((ext_vector_type(4))) float;
using s16x8 = __attribute__((ext_vector_type(8))) short;
using u16x4 = __attribute__((ext_vector_type(4))) unsigned short;
using u32x2 = __attribute__((ext_vector_type(2))) unsigned int;
using u32x4 = __attribute__((ext_vector_type(4))) unsigned int;
typedef unsigned short u16;
typedef unsigned int u32;

#define MFMA16(a, b, c) __builtin_amdgcn_mfma_f32_16x16x32_bf16(a, b, c, 0, 0, 0)
#define LOG2E 1.4426950408889634f
#define SQRTC 19.595917942265423f

__device__ __forceinline__ u16 f2bf(float f) {
  u32 u = __float_as_uint(f);
  u += 0x7fffu + ((u >> 16) & 1u);   // RNE
  return (u16)(u >> 16);
}

__device__ __forceinline__ u32 cvtpk(float lo, float hi) {
  u32 r;
  asm("v_cvt_pk_bf16_f32 %0, %1, %2" : "=v"(r) : "v"(lo), "v"(hi));
  return r;
}

__device__ __forceinline__ float fexp2(float x) {  // 2^x, single v_exp_f32
  float r;
  asm("v_exp_f32 %0, %1" : "=v"(r) : "v"(x));
  return r;
}

__device__ __forceinline__ void gld16(const void* g, void* l) {
  __builtin_amdgcn_global_load_lds((const __attribute__((address_space(1))) void*)g,
                                   (__attribute__((address_space(3))) void*)l, 16, 0, 0);
}

// --------------------------- fp32 -> bf16 convert (both weights) ------------
__global__ __launch_bounds__(256) void k_cvt2(const float* __restrict__ A,
                                              u16* __restrict__ Oa,
                                              const float* __restrict__ B,
                                              u16* __restrict__ Ob) {
  const int bid = blockIdx.x;
  const float* in;
  u16* out;
  size_t i;
  if (bid < 432) { in = A; out = Oa; i = (size_t)bid * 256 + threadIdx.x; }
  else           { in = B; out = Ob; i = (size_t)(bid - 432) * 256 + threadIdx.x; }
  f32x4 v = *(const f32x4*)(in + i * 4);
  u16x4 o;
  o[0] = f2bf(v[0]); o[1] = f2bf(v[1]); o[2] = f2bf(v[2]); o[3] = f2bf(v[3]);
  *(u16x4*)(out + i * 4) = o;
}

// --------------------------- QKV GEMM (M=16384,N=1152,K=384) ----------------
__global__ __launch_bounds__(256) void k_qkv(const float* __restrict__ X,
                                             const u16* __restrict__ W,
                                             const float* __restrict__ temp,
                                             u16* __restrict__ Qt,
                                             u16* __restrict__ Kb,
                                             u16* __restrict__ Vt) {
  __shared__ u16 As[2][128 * 32];
  __shared__ u16 Bs[2][128 * 32];
  const int tid = threadIdx.x, w = tid >> 6, l = tid & 63, lr = l & 15, lg = l >> 4;
  const int id = blockIdx.y * 9 + blockIdx.x;
  const int swz = (id & 7) * 144 + (id >> 3);
  const int tn = (swz % 9) * 128, tm = (swz / 9) * 128;
  const int wr = w >> 1, wc = w & 1;
  const int r0 = tid >> 2, c8 = (tid & 3) * 8;
  const int ar = tid >> 1, ac = (tid & 1) * 16;

  f32x4 acc[4][4] = {};
  f32x4 a4[4];

  auto issueA = [&](int kt) {
    const float* xp = X + (size_t)(tm + ar) * 384 + kt * 32 + ac;
    a4[0] = *(const f32x4*)(xp);
    a4[1] = *(const f32x4*)(xp + 4);
    a4[2] = *(const f32x4*)(xp + 8);
    a4[3] = *(const f32x4*)(xp + 12);
  };
  auto commitA = [&](int buf) {
    u32x4 h0, h1;
    h0[0] = cvtpk(a4[0][0], a4[0][1]); h0[1] = cvtpk(a4[0][2], a4[0][3]);
    h0[2] = cvtpk(a4[1][0], a4[1][1]); h0[3] = cvtpk(a4[1][2], a4[1][3]);
    h1[0] = cvtpk(a4[2][0], a4[2][1]); h1[1] = cvtpk(a4[2][2], a4[2][3]);
    h1[2] = cvtpk(a4[3][0], a4[3][1]); h1[3] = cvtpk(a4[3][2], a4[3][3]);
    *(u32x4*)&As[buf][ar * 32 + ac] = h0;
    *(u32x4*)&As[buf][ar * 32 + ac + 8] = h1;
  };
  auto stageB = [&](int buf, int kt) {
    const int k0 = kt * 32;
    char* db = (char*)(&Bs[buf][0]) + (w << 10);
    gld16(W + (size_t)(tn + r0) * 384 + k0 + c8, db);
    gld16(W + (size_t)(tn + 64 + r0) * 384 + k0 + c8, db + 4096);
  };

  issueA(0); stageB(0, 0); commitA(0);
  for (int kt = 0; kt < 12; ++kt) {
    __syncthreads();
    if (kt < 11) { issueA(kt + 1); stageB((kt + 1) & 1, kt + 1); }
    const int buf = kt & 1;
    s16x8 af[4], bfr[4];
    for (int mi = 0; mi < 4; mi++)
      af[mi] = *(const s16x8*)&As[buf][(wr * 64 + mi * 16 + lr) * 32 + lg * 8];
    for (int ni = 0; ni < 4; ni++)
      bfr[ni] = *(const s16x8*)&Bs[buf][(wc * 64 + ni * 16 + lr) * 32 + lg * 8];
    for (int mi = 0; mi < 4; mi++)
      for (int ni = 0; ni < 4; ni++)
        acc[mi][ni] = MFMA16(af[mi], bfr[ni], acc[mi][ni]);
    if (kt < 11) commitA((kt + 1) & 1);
  }

  const int which = (tn + wc * 64) / 384;
  const int bidx = (tm >> 11);
  for (int mi = 0; mi < 4; mi++)
    for (int ni = 0; ni < 4; ni++) {
      const int n = tn + wc * 64 + ni * 16 + lr;
      const int c = n - which * 384;
      const int h = c >> 6, d = c & 63;
      const size_t bh = (size_t)(bidx * 6 + h);
      if (which == 1) {
        for (int j = 0; j < 4; j++) {
          const int pos = (tm + wr * 64 + mi * 16 + lg * 4 + j) & 2047;
          Kb[(bh * 2048 + pos) * 64 + d] = f2bf(acc[mi][ni][j]);
        }
      } else {
        const float mult = (which == 0) ? (LOG2E / (SQRTC * temp[h])) : 1.0f;
        const int pos0 = (tm + wr * 64 + mi * 16 + lg * 4) & 2047;
        u16x4 vv;
        vv[0] = f2bf(acc[mi][ni][0] * mult); vv[1] = f2bf(acc[mi][ni][1] * mult);
        vv[2] = f2bf(acc[mi][ni][2] * mult); vv[3] = f2bf(acc[mi][ni][3] * mult);
        u16* dst = (which == 0) ? Qt : Vt;
        *(u16x4*)&dst[(bh * 64 + d) * 2048 + pos0] = vv;
      }
    }
}

// --------------------------- Flash attention (pipelined) --------------------
// grid = 48 bh * 16 q-tiles (XCD-swizzled). Block: 4 waves x 32 q-rows.
// K and V: dbuf XOR-swizzled LDS via global_load_lds w/ pre-swizzled source.
// Pipeline: pack(t) || QK^T(t+1); K prefetch dist 2, V dist 1.
__global__ __launch_bounds__(256, 3) void k_attn(const u16* __restrict__ Qt,
                                                 const u16* __restrict__ Kb,
                                                 const u16* __restrict__ Vt,
                                                 u16* __restrict__ AO) {
  __shared__ u16 Ks[2][64 * 64];
  __shared__ u16 Vs[2][64 * 64];
  __shared__ u16 Ps[4][32 * 72];
  const int tid = threadIdx.x, w = tid >> 6, l = tid & 63, lr = l & 15, lg = l >> 4;
  const int orig = blockIdx.x;
  const int rm = (orig & 7) * 96 + (orig >> 3);
  const int qt = rm & 15, bh = rm >> 4;
  const int h = bh % 6, b = bh / 6;
  const size_t base = (size_t)bh << 17;
  const int q0 = qt * 128 + w * 32;
  const int maskKt = q0 >> 6;
  const int qo = q0 & 63;

  // Q fragments gathered from Qt[bh][d][pos] (once per block)
  s16x8 qf[2][2];
  for (int mi = 0; mi < 2; mi++)
    for (int ks = 0; ks < 2; ks++) {
      const u16* qp = Qt + base + (size_t)(ks * 32 + lg * 8) * 2048 + q0 + mi * 16 + lr;
      s16x8 q;
      for (int e = 0; e < 8; ++e) q[e] = (short)qp[(size_t)e * 2048];
      qf[mi][ks] = q;
    }

  f32x4 o0[4] = {}, o1[4] = {};
  float sum0 = 0.f, sum1 = 0.f;

  // Staging via global_load_lds, pre-swizzled source: wave w writes LDS rows
  // [w*8, w*8+8) and [32+w*8, ...) linearly (lane l -> row w*8+(l>>3), chunk
  // l&7); fetch global chunk (l&7)^(row&7) so swizzled content lands linear.
  const int kr = w * 8 + (l >> 3);
  const int kc = (l & 7) ^ (kr & 7);
  auto gldK = [&](int kt) {
    const int buf = kt & 1;
    u16* kd0 = &Ks[buf][0] + w * 512;
    u16* kd1 = &Ks[buf][2048] + w * 512;
    gld16(Kb + base + (size_t)(kt * 64 + kr) * 64 + kc * 8, kd0);
    gld16(Kb + base + (size_t)(kt * 64 + 32 + kr) * 64 + kc * 8, kd1);
  };
  auto gldV = [&](int kt) {  // Vt rows are d (stride 2048); same swizzle
    const int buf = kt & 1;
    u16* vd0 = &Vs[buf][0] + w * 512;
    u16* vd1 = &Vs[buf][2048] + w * 512;
    gld16(Vt + base + (size_t)kr * 2048 + kt * 64 + kc * 8, vd0);
    gld16(Vt + base + (size_t)(32 + kr) * 2048 + kt * 64 + kc * 8, vd1);
  };

  const int lrs = (lr & 7) << 4;
  const int x0 = (lg * 16) ^ lrs;
  const int x1 = (64 + lg * 16) ^ lrs;

  auto qk = [&](int kt, f32x4 (&sn0)[4], f32x4 (&sn1)[4]) {
    const char* kbp = (const char*)&Ks[kt & 1][0];
    __builtin_amdgcn_s_setprio(1);
    for (int ni = 0; ni < 4; ++ni) {
      const int rb = (ni * 16 + lr) * 128;
      const s16x8 kf0 = *(const s16x8*)(kbp + (rb + x0));
      const s16x8 kf1 = *(const s16x8*)(kbp + (rb + x1));
      f32x4 z = {};
      sn0[ni] = MFMA16(kf0, qf[0][0], z);
      sn0[ni] = MFMA16(kf1, qf[0][1], sn0[ni]);
      sn1[ni] = MFMA16(kf0, qf[1][0], z);
      sn1[ni] = MFMA16(kf1, qf[1][1], sn1[ni]);
    }
    __builtin_amdgcn_s_setprio(0);
  };

  u16* const psw = &Ps[w][0];
  auto packHalf = [&](f32x4 (&st)[4], int rowoff, float& sum) {
    u16* pr = psw + (rowoff + lr) * 72 + lg * 4;
    float ls = 0.f;
    for (int ni = 0; ni < 4; ++ni) {
      float p0 = fexp2(st[ni][0]), p1 = fexp2(st[ni][1]);
      float p2 = fexp2(st[ni][2]), p3 = fexp2(st[ni][3]);
      ls += (p0 + p1) + (p2 + p3);
      u32x2 d2;
      d2[0] = cvtpk(p0, p1);
      d2[1] = cvtpk(p2, p3);
      *(u32x2*)(pr + ni * 16) = d2;
    }
    ls += __shfl_xor(ls, 16);
    ls += __shfl_xor(ls, 32);
    sum += ls;
  };
  auto maskDiag = [&](f32x4 (&s0)[4], f32x4 (&s1)[4]) {
    for (int ni = 0; ni < 4; ++ni)
      for (int j = 0; j < 4; ++j) {
        const int kvl = ni * 16 + lg * 4 + j;
        if (kvl == qo + lr)      s0[ni][j] = -1e30f;
        if (kvl == qo + 16 + lr) s1[ni][j] = -1e30f;
      }
  };
  auto pv = [&](int t) {
    const char* vbp = (const char*)&Vs[t & 1][0];
    const s16x8 pa0k0 = *(const s16x8*)((const char*)(psw + lr * 72) + 0 * 64 + lg * 16);
    const s16x8 pa0k1 = *(const s16x8*)((const char*)(psw + lr * 72) + 1 * 64 + lg * 16);
    const s16x8 pa1k0 = *(const s16x8*)((const char*)(psw + (16 + lr) * 72) + 0 * 64 + lg * 16);
    const s16x8 pa1k1 = *(const s16x8*)((const char*)(psw + (16 + lr) * 72) + 1 * 64 + lg * 16);
    __builtin_amdgcn_s_setprio(1);
    for (int dj = 0; dj < 4; ++dj) {
      const s16x8 vf0 = *(const s16x8*)(vbp + ((dj * 16 + lr) * 128 + x0));
      const s16x8 vf1 = *(const s16x8*)(vbp + ((dj * 16 + lr) * 128 + x1));
      o0[dj] = MFMA16(pa0k0, vf0, o0[dj]);
      o0[dj] = MFMA16(pa0k1, vf1, o0[dj]);
      o1[dj] = MFMA16(pa1k0, vf0, o1[dj]);
      o1[dj] = MFMA16(pa1k1, vf1, o1[dj]);
    }
    __builtin_amdgcn_s_setprio(0);
  };

  f32x4 stA0[4], stA1[4], stB0[4], stB1[4];

  // ---- prologue ----
  gldK(0); gldV(0);
  __syncthreads();                 // Ks[0], Vs[0] ready
  gldK(1);
  qk(0, stA0, stA1);               // S(0) from Ks[0]
  __syncthreads();                 // Ks[1] ready; qk(0) reads drained

  // ---- pipelined loop ----
  auto body = [&](f32x4 (&sc0)[4], f32x4 (&sc1)[4],
                  f32x4 (&sn0)[4], f32x4 (&sn1)[4], int t) {
    if (t < 30) gldK(t + 2);       // -> Ks[t&1] (qk(t) done last body)
    gldV(t + 1);                   // -> Vs[(t+1)&1] (pv(t-1) done last body)
    if (t == maskKt) maskDiag(sc0, sc1);
    packHalf(sc0, 0, sum0);        // exp2/pack overlaps qk(t+1) MFMAs
    qk(t + 1, sn0, sn1);
    packHalf(sc1, 16, sum1);
    pv(t);                         // Vs[t&1], Ps of this tile
    __syncthreads();               // drains gld16s; next-tile buffers ready
  };

  for (int tb = 0; tb < 15; ++tb) {
    body(stA0, stA1, stB0, stB1, 2 * tb);
    body(stB0, stB1, stA0, stA1, 2 * tb + 1);
  }
  body(stA0, stA1, stB0, stB1, 30);
  // ---- tail: tile 31 ----
  if (31 == maskKt) maskDiag(stB0, stB1);
  packHalf(stB0, 0, sum0);
  packHalf(stB1, 16, sum1);
  pv(31);

  // ---- normalize + merge heads: AO[b][pos][h*64+d], bf16 ----
  f32x4 rv0, rv1;
  for (int j = 0; j < 4; ++j) {
    rv0[j] = 1.0f / __shfl(sum0, lg * 4 + j);
    rv1[j] = 1.0f / __shfl(sum1, lg * 4 + j);
  }
  const size_t aobase = (size_t)b * 2048 * 384 + (size_t)h * 64;
  for (int j = 0; j < 4; ++j) {
    const int pos0 = q0 + lg * 4 + j;
    const int pos1 = pos0 + 16;
    for (int dj = 0; dj < 4; ++dj) {
      AO[aobase + (size_t)pos0 * 384 + dj * 16 + lr] = f2bf(o0[dj][j] * rv0[j]);
      AO[aobase + (size_t)pos1 * 384 + dj * 16 + lr] = f2bf(o1[dj][j] * rv1[j]);
    }
  }
}

// --------------------------- Proj GEMM (M=16384,N=384,K=384) ----------------
__global__ __launch_bounds__(256) void k_proj(const u16* __restrict__ A,
                                              const u16* __restrict__ W,
                                              const float* __restrict__ bias,
                                              float* __restrict__ out) {
  __shared__ u16 As[2][128 * 32];
  __shared__ u16 Bs[2][64 * 32];
  const int tid = threadIdx.x, w = tid >> 6, l = tid & 63, lr = l & 15, lg = l >> 4;
  const int id = blockIdx.y * 6 + blockIdx.x;
  const int swz = (id & 7) * 96 + (id >> 3);
  const int tn = (swz % 6) * 64, tm = (swz / 6) * 128;
  const int r0 = tid >> 2, c8 = (tid & 3) * 8;

  f32x4 acc[2][4] = {};

  auto stage = [&](int buf, int kt) {
    const int k0 = kt * 32;
    char* da = (char*)(&As[buf][0]) + (w << 10);
    char* db = (char*)(&Bs[buf][0]) + (w << 10);
    gld16(A + (size_t)(tm + r0) * 384 + k0 + c8, da);
    gld16(A + (size_t)(tm + 64 + r0) * 384 + k0 + c8, da + 4096);
    gld16(W + (size_t)(tn + r0) * 384 + k0 + c8, db);
  };

  stage(0, 0);
  for (int kt = 0; kt < 12; ++kt) {
    __syncthreads();
    if (kt < 11) stage((kt + 1) & 1, kt + 1);
    const int buf = kt & 1;
    s16x8 af[2], bfr[4];
    for (int mi = 0; mi < 2; mi++)
      af[mi] = *(const s16x8*)&As[buf][(w * 32 + mi * 16 + lr) * 32 + lg * 8];
    for (int ni = 0; ni < 4; ni++)
      bfr[ni] = *(const s16x8*)&Bs[buf][(ni * 16 + lr) * 32 + lg * 8];
    for (int mi = 0; mi < 2; mi++)
      for (int ni = 0; ni < 4; ni++)
        acc[mi][ni] = MFMA16(af[mi], bfr[ni], acc[mi][ni]);
  }

  for (int mi = 0; mi < 2; mi++)
    for (int ni = 0; ni < 4; ni++) {
      const int n = tn + ni * 16 + lr;
      const float bn = bias[n];
      for (int j = 0; j < 4; j++) {
        const int m = tm + w * 32 + mi * 16 + lg * 4 + j;
        out[(size_t)m * 384 + n] = acc[mi][ni][j] + bn;
      }
    }
}

// --------------------------- launch -----------------------------------------
extern "C" void kernel_launch(void* const* d_in, const int* in_sizes, int n_in,
                              void* d_out, int out_size, void* d_ws, size_t ws_size,
                              hipStream_t stream) {
  const float* x      = (const float*)d_in[0];  // [8,2048,384]
  const float* qkv_w  = (const float*)d_in[1];  // [1152,384]
  const float* proj_w = (const float*)d_in[2];  // [384,384]
  const float* proj_b = (const float*)d_in[3];  // [384]
  const float* temp   = (const float*)d_in[4];  // [6]
  float* out = (float*)d_out;

  u16* wqkvb  = (u16*)d_ws;            // 442368
  u16* wprojb = wqkvb + 442368;        // 147456
  u16* Qt     = wprojb + 147456;       // 6291456
  u16* Kb     = Qt + 6291456;          // 6291456
  u16* Vtb    = Kb + 6291456;          // 6291456
  u16* AOb    = Vtb + 6291456;         // 6291456

  k_cvt2<<<576, 256, 0, stream>>>(qkv_w, wqkvb, proj_w, wprojb);
  k_qkv<<<dim3(9, 128), 256, 0, stream>>>(x, wqkvb, temp, Qt, Kb, Vtb);
  k_attn<<<768, 256, 0, stream>>>(Qt, Kb, Vtb, AOb);
  k_proj<<<dim3(6, 128), 256, 0, stream>>>(AOb, wprojb, proj_b, out);
}

// Round 10
// 121.908 us; speedup vs baseline: 2.4732x; 1.0709x over previous
//
#include <hip/hip_runtime.h>

// ---------------------------------------------------------------------------
// LocalitySelfAttention: y = proj( attn(x@Wqkv^T) ) for B=8,N=2048,C=384,H=6
// All internal compute bf16 MFMA + fp32 accum. Output fp32.
// R10: revert attn to R7 structure (reg-staged K/V crossing barriers freely;
// R8/R9 pipelines regressed via vmcnt-drain + overfetch). One change: Ps
// pad->XOR-swizzle, LDS 50->48KB (occupancy granularity hypothesis).
// ---------------------------------------------------------------------------

using f32x4 = __attribute__((ext_vector_type(4))) float;
using s16x8 = __attribute__((ext_vector_type(8))) short;
using u16x4 = __attribute__((ext_vector_type(4))) unsigned short;
using u32x2 = __attribute__((ext_vector_type(2))) unsigned int;
using u32x4 = __attribute__((ext_vector_type(4))) unsigned int;
typedef unsigned short u16;
typedef unsigned int u32;

#define MFMA16(a, b, c) __builtin_amdgcn_mfma_f32_16x16x32_bf16(a, b, c, 0, 0, 0)
#define LOG2E 1.4426950408889634f
#define SQRTC 19.595917942265423f

__device__ __forceinline__ u16 f2bf(float f) {
  u32 u = __float_as_uint(f);
  u += 0x7fffu + ((u >> 16) & 1u);   // RNE
  return (u16)(u >> 16);
}

__device__ __forceinline__ u32 cvtpk(float lo, float hi) {
  u32 r;
  asm("v_cvt_pk_bf16_f32 %0, %1, %2" : "=v"(r) : "v"(lo), "v"(hi));
  return r;
}

__device__ __forceinline__ float fexp2(float x) {  // 2^x, single v_exp_f32
  float r;
  asm("v_exp_f32 %0, %1" : "=v"(r) : "v"(x));
  return r;
}

__device__ __forceinline__ void gld16(const void* g, void* l) {
  __builtin_amdgcn_global_load_lds((const __attribute__((address_space(1))) void*)g,
                                   (__attribute__((address_space(3))) void*)l, 16, 0, 0);
}

// --------------------------- fp32 -> bf16 convert (both weights) ------------
__global__ __launch_bounds__(256) void k_cvt2(const float* __restrict__ A,
                                              u16* __restrict__ Oa,
                                              const float* __restrict__ B,
                                              u16* __restrict__ Ob) {
  const int bid = blockIdx.x;
  const float* in;
  u16* out;
  size_t i;
  if (bid < 432) { in = A; out = Oa; i = (size_t)bid * 256 + threadIdx.x; }
  else           { in = B; out = Ob; i = (size_t)(bid - 432) * 256 + threadIdx.x; }
  f32x4 v = *(const f32x4*)(in + i * 4);
  u16x4 o;
  o[0] = f2bf(v[0]); o[1] = f2bf(v[1]); o[2] = f2bf(v[2]); o[3] = f2bf(v[3]);
  *(u16x4*)(out + i * 4) = o;
}

// --------------------------- QKV GEMM (M=16384,N=1152,K=384) ----------------
__global__ __launch_bounds__(256) void k_qkv(const float* __restrict__ X,
                                             const u16* __restrict__ W,
                                             const float* __restrict__ temp,
                                             u16* __restrict__ Qt,
                                             u16* __restrict__ Kb,
                                             u16* __restrict__ Vt) {
  __shared__ u16 As[2][128 * 32];
  __shared__ u16 Bs[2][128 * 32];
  const int tid = threadIdx.x, w = tid >> 6, l = tid & 63, lr = l & 15, lg = l >> 4;
  const int id = blockIdx.y * 9 + blockIdx.x;
  const int swz = (id & 7) * 144 + (id >> 3);
  const int tn = (swz % 9) * 128, tm = (swz / 9) * 128;
  const int wr = w >> 1, wc = w & 1;
  const int r0 = tid >> 2, c8 = (tid & 3) * 8;
  const int ar = tid >> 1, ac = (tid & 1) * 16;

  f32x4 acc[4][4] = {};
  f32x4 a4[4];

  auto issueA = [&](int kt) {
    const float* xp = X + (size_t)(tm + ar) * 384 + kt * 32 + ac;
    a4[0] = *(const f32x4*)(xp);
    a4[1] = *(const f32x4*)(xp + 4);
    a4[2] = *(const f32x4*)(xp + 8);
    a4[3] = *(const f32x4*)(xp + 12);
  };
  auto commitA = [&](int buf) {
    u32x4 h0, h1;
    h0[0] = cvtpk(a4[0][0], a4[0][1]); h0[1] = cvtpk(a4[0][2], a4[0][3]);
    h0[2] = cvtpk(a4[1][0], a4[1][1]); h0[3] = cvtpk(a4[1][2], a4[1][3]);
    h1[0] = cvtpk(a4[2][0], a4[2][1]); h1[1] = cvtpk(a4[2][2], a4[2][3]);
    h1[2] = cvtpk(a4[3][0], a4[3][1]); h1[3] = cvtpk(a4[3][2], a4[3][3]);
    *(u32x4*)&As[buf][ar * 32 + ac] = h0;
    *(u32x4*)&As[buf][ar * 32 + ac + 8] = h1;
  };
  auto stageB = [&](int buf, int kt) {
    const int k0 = kt * 32;
    char* db = (char*)(&Bs[buf][0]) + (w << 10);
    gld16(W + (size_t)(tn + r0) * 384 + k0 + c8, db);
    gld16(W + (size_t)(tn + 64 + r0) * 384 + k0 + c8, db + 4096);
  };

  issueA(0); stageB(0, 0); commitA(0);
  for (int kt = 0; kt < 12; ++kt) {
    __syncthreads();
    if (kt < 11) { issueA(kt + 1); stageB((kt + 1) & 1, kt + 1); }
    const int buf = kt & 1;
    s16x8 af[4], bfr[4];
    for (int mi = 0; mi < 4; mi++)
      af[mi] = *(const s16x8*)&As[buf][(wr * 64 + mi * 16 + lr) * 32 + lg * 8];
    for (int ni = 0; ni < 4; ni++)
      bfr[ni] = *(const s16x8*)&Bs[buf][(wc * 64 + ni * 16 + lr) * 32 + lg * 8];
    for (int mi = 0; mi < 4; mi++)
      for (int ni = 0; ni < 4; ni++)
        acc[mi][ni] = MFMA16(af[mi], bfr[ni], acc[mi][ni]);
    if (kt < 11) commitA((kt + 1) & 1);
  }

  const int which = (tn + wc * 64) / 384;
  const int bidx = (tm >> 11);
  for (int mi = 0; mi < 4; mi++)
    for (int ni = 0; ni < 4; ni++) {
      const int n = tn + wc * 64 + ni * 16 + lr;
      const int c = n - which * 384;
      const int h = c >> 6, d = c & 63;
      const size_t bh = (size_t)(bidx * 6 + h);
      if (which == 1) {
        for (int j = 0; j < 4; j++) {
          const int pos = (tm + wr * 64 + mi * 16 + lg * 4 + j) & 2047;
          Kb[(bh * 2048 + pos) * 64 + d] = f2bf(acc[mi][ni][j]);
        }
      } else {
        const float mult = (which == 0) ? (LOG2E / (SQRTC * temp[h])) : 1.0f;
        const int pos0 = (tm + wr * 64 + mi * 16 + lg * 4) & 2047;
        u16x4 vv;
        vv[0] = f2bf(acc[mi][ni][0] * mult); vv[1] = f2bf(acc[mi][ni][1] * mult);
        vv[2] = f2bf(acc[mi][ni][2] * mult); vv[3] = f2bf(acc[mi][ni][3] * mult);
        u16* dst = (which == 0) ? Qt : Vt;
        *(u16x4*)&dst[(bh * 64 + d) * 2048 + pos0] = vv;
      }
    }
}

// --------------------------- Flash attention (R7 structure) -----------------
// grid = 48 bh * 16 q-tiles (XCD-swizzled). Block: 4 waves x 32 q-rows.
// K/V: reg-staged dbuf XOR-swizzled LDS (loads cross barriers freely).
// P = exp2(t) directly; row-sum via ones-MFMA. Ps XOR-swizzled (48KB LDS).
#define LDSOFF(row, c16) (((row) * 128 + (c16) * 16) ^ (((row) & 7) << 4))

__global__ __launch_bounds__(256, 3) void k_attn(const u16* __restrict__ Qt,
                                                 const u16* __restrict__ Kb,
                                                 const u16* __restrict__ Vt,
                                                 u16* __restrict__ AO) {
  __shared__ u16 Ks[2][64 * 64];
  __shared__ u16 Vs[2][64 * 64];
  __shared__ u16 Ps[4][32 * 64];
  const int tid = threadIdx.x, w = tid >> 6, l = tid & 63, lr = l & 15, lg = l >> 4;
  const int orig = blockIdx.x;
  const int rm = (orig & 7) * 96 + (orig >> 3);
  const int qt = rm & 15, bh = rm >> 4;
  const int h = bh % 6, b = bh / 6;
  const size_t base = (size_t)bh << 17;
  const int q0 = qt * 128 + w * 32;
  const int maskKt = q0 >> 6;
  const int qo = q0 & 63;

  // Q fragments gathered from Qt[bh][d][pos] (once per block)
  s16x8 qf[2][2];
  for (int mi = 0; mi < 2; mi++)
    for (int ks = 0; ks < 2; ks++) {
      const u16* qp = Qt + base + (size_t)(ks * 32 + lg * 8) * 2048 + q0 + mi * 16 + lr;
      s16x8 q;
      for (int e = 0; e < 8; ++e) q[e] = (short)qp[(size_t)e * 2048];
      qf[mi][ks] = q;
    }

  s16x8 ones;
  for (int e = 0; e < 8; ++e) ones[e] = (short)0x3F80;  // bf16 1.0

  f32x4 o0[4] = {}, o1[4] = {};
  f32x4 os0 = {}, os1 = {};   // P row sums, MFMA-accumulated across tiles

  const int r0 = tid >> 3, c0 = tid & 7;
  const int c8 = c0 * 8;
  const int wo0 = LDSOFF(r0, c0), wo1 = LDSOFF(r0 + 32, c0);

  s16x8 ka0, ka1, va0, va1;
  auto issue = [&](int kt) {
    const u16* kp = Kb + base + (size_t)(kt * 64 + r0) * 64 + c8;
    ka0 = *(const s16x8*)kp;
    ka1 = *(const s16x8*)(kp + 32 * 64);
    const u16* vp = Vt + base + (size_t)r0 * 2048 + kt * 64 + c8;
    va0 = *(const s16x8*)vp;
    va1 = *(const s16x8*)(vp + 32 * 2048);
  };
  auto commit = [&](int buf) {
    char* kd = (char*)&Ks[buf][0];
    char* vd = (char*)&Vs[buf][0];
    *(s16x8*)(kd + wo0) = ka0; *(s16x8*)(kd + wo1) = ka1;
    *(s16x8*)(vd + wo0) = va0; *(s16x8*)(vd + wo1) = va1;
  };

  issue(0); commit(0);
  __syncthreads();

  const int lrs = (lr & 7) << 4;
  const int x0 = (lg * 16) ^ lrs;
  const int x1 = (64 + lg * 16) ^ lrs;

  // Ps byte offsets (swizzled [32][64] u16 rows of 128 B):
  char* const psb = (char*)&Ps[w][0];
  const int pw0 = (lg * 8 + 0 * 32) ^ lrs;   // pack write, ni=0 (u32x2, 8B)
  // pack writes use (lg*8 + ni*32) ^ lrs at row*128
  // pv reads use (ks*64 + lg*16) ^ lrs at row*128

  for (int kt = 0; kt < 32; ++kt) {
    const int cur = kt & 1;
    if (kt < 31) issue(kt + 1);

    // ---- S^T = K Q^T : D[row=kv][col=q] ----
    f32x4 st0[4] = {}, st1[4] = {};
    const char* kbp = (const char*)&Ks[cur][0];
    __builtin_amdgcn_s_setprio(1);
    for (int ni = 0; ni < 4; ++ni) {
      const int rb = (ni * 16 + lr) * 128;
      const s16x8 kf0 = *(const s16x8*)(kbp + (rb + x0));
      const s16x8 kf1 = *(const s16x8*)(kbp + (rb + x1));
      st0[ni] = MFMA16(kf0, qf[0][0], st0[ni]);
      st0[ni] = MFMA16(kf1, qf[0][1], st0[ni]);
      st1[ni] = MFMA16(kf0, qf[1][0], st1[ni]);
      st1[ni] = MFMA16(kf1, qf[1][1], st1[ni]);
    }
    __builtin_amdgcn_s_setprio(0);

    // ---- diagonal mask: only one tile intersects ----
    if (kt == maskKt) {
      for (int ni = 0; ni < 4; ++ni)
        for (int j = 0; j < 4; ++j) {
          const int kvl = ni * 16 + lg * 4 + j;
          if (kvl == qo + lr)      st0[ni][j] = -1e30f;
          if (kvl == qo + 16 + lr) st1[ni][j] = -1e30f;
        }
    }

    // ---- hoist V fragments to regs (independent of Ps) ----
    const char* vbp = (const char*)&Vs[cur][0];
    s16x8 vfr[2][4];
    for (int ks = 0; ks < 2; ++ks) {
      const int xk = ks ? x1 : x0;
      for (int dj = 0; dj < 4; ++dj)
        vfr[ks][dj] = *(const s16x8*)(vbp + ((dj * 16 + lr) * 128 + xk));
    }

    // ---- pack half 0 (q rows 0-15), swizzled Ps ----
    {
      char* pr = psb + lr * 128;
      for (int ni = 0; ni < 4; ++ni) {
        u32x2 d2;
        d2[0] = cvtpk(fexp2(st0[ni][0]), fexp2(st0[ni][1]));
        d2[1] = cvtpk(fexp2(st0[ni][2]), fexp2(st0[ni][3]));
        *(u32x2*)(pr + ((lg * 8 + ni * 32) ^ lrs)) = d2;
      }
    }
    // ---- PV half 0 ----
    {
      const s16x8 pa0k0 = *(const s16x8*)(psb + lr * 128 + ((0 * 64 + lg * 16) ^ lrs));
      const s16x8 pa0k1 = *(const s16x8*)(psb + lr * 128 + ((1 * 64 + lg * 16) ^ lrs));
      __builtin_amdgcn_s_setprio(1);
      for (int dj = 0; dj < 4; ++dj) o0[dj] = MFMA16(pa0k0, vfr[0][dj], o0[dj]);
      os0 = MFMA16(pa0k0, ones, os0);
      for (int dj = 0; dj < 4; ++dj) o0[dj] = MFMA16(pa0k1, vfr[1][dj], o0[dj]);
      os0 = MFMA16(pa0k1, ones, os0);
      __builtin_amdgcn_s_setprio(0);
    }
    // ---- pack half 1 (q rows 16-31) ----
    {
      char* pr = psb + (16 + lr) * 128;
      for (int ni = 0; ni < 4; ++ni) {
        u32x2 d2;
        d2[0] = cvtpk(fexp2(st1[ni][0]), fexp2(st1[ni][1]));
        d2[1] = cvtpk(fexp2(st1[ni][2]), fexp2(st1[ni][3]));
        *(u32x2*)(pr + ((lg * 8 + ni * 32) ^ lrs)) = d2;
      }
    }
    // ---- PV half 1 ----
    {
      const s16x8 pa1k0 = *(const s16x8*)(psb + (16 + lr) * 128 + ((0 * 64 + lg * 16) ^ lrs));
      const s16x8 pa1k1 = *(const s16x8*)(psb + (16 + lr) * 128 + ((1 * 64 + lg * 16) ^ lrs));
      __builtin_amdgcn_s_setprio(1);
      for (int dj = 0; dj < 4; ++dj) o1[dj] = MFMA16(pa1k0, vfr[0][dj], o1[dj]);
      os1 = MFMA16(pa1k0, ones, os1);
      for (int dj = 0; dj < 4; ++dj) o1[dj] = MFMA16(pa1k1, vfr[1][dj], o1[dj]);
      os1 = MFMA16(pa1k1, ones, os1);
      __builtin_amdgcn_s_setprio(0);
    }

    if (kt < 31) commit(cur ^ 1);
    __syncthreads();
  }

  // ---- normalize + merge heads: AO[b][pos][h*64+d], bf16 ----
  f32x4 rv0, rv1;
  for (int j = 0; j < 4; ++j) { rv0[j] = 1.0f / os0[j]; rv1[j] = 1.0f / os1[j]; }
  const size_t aobase = (size_t)b * 2048 * 384 + (size_t)h * 64;
  for (int j = 0; j < 4; ++j) {
    const int pos0 = q0 + lg * 4 + j;
    const int pos1 = pos0 + 16;
    for (int dj = 0; dj < 4; ++dj) {
      AO[aobase + (size_t)pos0 * 384 + dj * 16 + lr] = f2bf(o0[dj][j] * rv0[j]);
      AO[aobase + (size_t)pos1 * 384 + dj * 16 + lr] = f2bf(o1[dj][j] * rv1[j]);
    }
  }
}

// --------------------------- Proj GEMM (M=16384,N=384,K=384) ----------------
__global__ __launch_bounds__(256) void k_proj(const u16* __restrict__ A,
                                              const u16* __restrict__ W,
                                              const float* __restrict__ bias,
                                              float* __restrict__ out) {
  __shared__ u16 As[2][128 * 32];
  __shared__ u16 Bs[2][64 * 32];
  const int tid = threadIdx.x, w = tid >> 6, l = tid & 63, lr = l & 15, lg = l >> 4;
  const int id = blockIdx.y * 6 + blockIdx.x;
  const int swz = (id & 7) * 96 + (id >> 3);
  const int tn = (swz % 6) * 64, tm = (swz / 6) * 128;
  const int r0 = tid >> 2, c8 = (tid & 3) * 8;

  f32x4 acc[2][4] = {};

  auto stage = [&](int buf, int kt) {
    const int k0 = kt * 32;
    char* da = (char*)(&As[buf][0]) + (w << 10);
    char* db = (char*)(&Bs[buf][0]) + (w << 10);
    gld16(A + (size_t)(tm + r0) * 384 + k0 + c8, da);
    gld16(A + (size_t)(tm + 64 + r0) * 384 + k0 + c8, da + 4096);
    gld16(W + (size_t)(tn + r0) * 384 + k0 + c8, db);
  };

  stage(0, 0);
  for (int kt = 0; kt < 12; ++kt) {
    __syncthreads();
    if (kt < 11) stage((kt + 1) & 1, kt + 1);
    const int buf = kt & 1;
    s16x8 af[2], bfr[4];
    for (int mi = 0; mi < 2; mi++)
      af[mi] = *(const s16x8*)&As[buf][(w * 32 + mi * 16 + lr) * 32 + lg * 8];
    for (int ni = 0; ni < 4; ni++)
      bfr[ni] = *(const s16x8*)&Bs[buf][(ni * 16 + lr) * 32 + lg * 8];
    for (int mi = 0; mi < 2; mi++)
      for (int ni = 0; ni < 4; ni++)
        acc[mi][ni] = MFMA16(af[mi], bfr[ni], acc[mi][ni]);
  }

  for (int mi = 0; mi < 2; mi++)
    for (int ni = 0; ni < 4; ni++) {
      const int n = tn + ni * 16 + lr;
      const float bn = bias[n];
      for (int j = 0; j < 4; j++) {
        const int m = tm + w * 32 + mi * 16 + lg * 4 + j;
        out[(size_t)m * 384 + n] = acc[mi][ni][j] + bn;
      }
    }
}

// --------------------------- launch -----------------------------------------
extern "C" void kernel_launch(void* const* d_in, const int* in_sizes, int n_in,
                              void* d_out, int out_size, void* d_ws, size_t ws_size,
                              hipStream_t stream) {
  const float* x      = (const float*)d_in[0];  // [8,2048,384]
  const float* qkv_w  = (const float*)d_in[1];  // [1152,384]
  const float* proj_w = (const float*)d_in[2];  // [384,384]
  const float* proj_b = (const float*)d_in[3];  // [384]
  const float* temp   = (const float*)d_in[4];  // [6]
  float* out = (float*)d_out;

  u16* wqkvb  = (u16*)d_ws;            // 442368
  u16* wprojb = wqkvb + 442368;        // 147456
  u16* Qt     = wprojb + 147456;       // 6291456
  u16* Kb     = Qt + 6291456;          // 6291456
  u16* Vtb    = Kb + 6291456;          // 6291456
  u16* AOb    = Vtb + 6291456;         // 6291456

  k_cvt2<<<576, 256, 0, stream>>>(qkv_w, wqkvb, proj_w, wprojb);
  k_qkv<<<dim3(9, 128), 256, 0, stream>>>(x, wqkvb, temp, Qt, Kb, Vtb);
  k_attn<<<768, 256, 0, stream>>>(Qt, Kb, Vtb, AOb);
  k_proj<<<dim3(6, 128), 256, 0, stream>>>(AOb, wprojb, proj_b, out);
}